// Round 3
// baseline (7980.242 us; speedup 1.0000x reference)
//
#include <hip/hip_runtime.h>
#include <hip/hip_bf16.h>
#include <stdint.h>

// B=64 T=64 E=256 S=128 ENC=1024 RNN=1024 ATT=1024 DENSE=8000
// Persistent recurrence: 256 blocks x 512 threads, 4 grid barriers/step.
// z-columns permuted: orig (g,r) -> p=(r>>4)*64 + g*16 + (r&15) so the 4
// MFMA col-fragments of a lane are the 4 gates of unit r=16T+lm.

#define PERSIST_NB 256

typedef __attribute__((ext_vector_type(8))) short short8;
typedef __attribute__((ext_vector_type(4))) float floatx4;
typedef __attribute__((ext_vector_type(4))) unsigned short ushortx4;

__device__ __forceinline__ float b2f(unsigned short u) {
    union { unsigned int i; float f; } v; v.i = ((unsigned int)u) << 16; return v.f;
}
__device__ __forceinline__ unsigned short f2b(float f) {
    union { float f; unsigned int i; } v; v.f = f;
    unsigned int r = v.i + 0x7fffu + ((v.i >> 16) & 1u);
    return (unsigned short)(r >> 16);
}
// clamp-free: e=exp(2x): x->+inf e=inf rcp=0 -> 1; x->-inf e=0 -> -1.
__device__ __forceinline__ float ftanh(float x) {
    float e = __expf(2.f * x);
    return 1.f - 2.f * __builtin_amdgcn_rcpf(e + 1.f);
}
__device__ __forceinline__ float fsig(float x) {
    return __builtin_amdgcn_rcpf(1.f + __expf(-x));
}
__device__ __forceinline__ void ld_lds16(const void* g, void* l) {
    __builtin_amdgcn_global_load_lds((const __attribute__((address_space(1))) void*)g,
                                     (__attribute__((address_space(3))) void*)l, 16, 0, 0);
}
__device__ __forceinline__ void unpack16(uint4 a, uint4 b, float* f) {
    f[0]=b2f((unsigned short)(a.x&0xffff)); f[1]=b2f((unsigned short)(a.x>>16));
    f[2]=b2f((unsigned short)(a.y&0xffff)); f[3]=b2f((unsigned short)(a.y>>16));
    f[4]=b2f((unsigned short)(a.z&0xffff)); f[5]=b2f((unsigned short)(a.z>>16));
    f[6]=b2f((unsigned short)(a.w&0xffff)); f[7]=b2f((unsigned short)(a.w>>16));
    f[8]=b2f((unsigned short)(b.x&0xffff)); f[9]=b2f((unsigned short)(b.x>>16));
    f[10]=b2f((unsigned short)(b.y&0xffff)); f[11]=b2f((unsigned short)(b.y>>16));
    f[12]=b2f((unsigned short)(b.z&0xffff)); f[13]=b2f((unsigned short)(b.z>>16));
    f[14]=b2f((unsigned short)(b.w&0xffff)); f[15]=b2f((unsigned short)(b.w>>16));
}

// sense-reversal grid barrier, agent scope. bar[0]=counter, bar[1]=generation.
__device__ __forceinline__ void gbar(unsigned int* bar) {
    __syncthreads();
    if (threadIdx.x == 0) {
        unsigned int g = __hip_atomic_load(&bar[1], __ATOMIC_RELAXED, __HIP_MEMORY_SCOPE_AGENT);
        __builtin_amdgcn_fence(__ATOMIC_RELEASE, "agent");   // publish this block's writes
        unsigned int a = __hip_atomic_fetch_add(&bar[0], 1u, __ATOMIC_RELAXED, __HIP_MEMORY_SCOPE_AGENT);
        if (a == PERSIST_NB - 1u) {
            __builtin_amdgcn_fence(__ATOMIC_ACQUIRE, "agent");
            __hip_atomic_store(&bar[0], 0u, __ATOMIC_RELAXED, __HIP_MEMORY_SCOPE_AGENT);
            __hip_atomic_store(&bar[1], g + 1u, __ATOMIC_RELEASE, __HIP_MEMORY_SCOPE_AGENT);
        } else {
            int guard = 0;
            while (__hip_atomic_load(&bar[1], __ATOMIC_RELAXED, __HIP_MEMORY_SCOPE_AGENT) == g &&
                   ++guard < (1 << 24))
                __builtin_amdgcn_s_sleep(2);
            __builtin_amdgcn_fence(__ATOMIC_ACQUIRE, "agent");
        }
    }
    __syncthreads();
}

// ---------------- f32 -> bf16 convert ----------------
__global__ __launch_bounds__(256) void conv_f32_bf16(
    const float* __restrict__ src, unsigned short* __restrict__ dst, int n4)
{
    int i = blockIdx.x * 256 + threadIdx.x;
    if (i < n4) {
        float4 v = ((const float4*)src)[i];
        ushortx4 o;
        o[0] = f2b(v.x); o[1] = f2b(v.y); o[2] = f2b(v.z); o[3] = f2b(v.w);
        ((ushortx4*)dst)[i] = o;
    }
}

// ------- transpose+convert: src[K][N] f32 -> dst[rowoff+perm(n)][coloff+k] bf16
__global__ __launch_bounds__(256) void transpose_conv(
    const float* __restrict__ src, int srcld,
    unsigned short* __restrict__ dst, int dstld, int coloff, int rowoff, int perm)
{
    __shared__ float tile[32][33];
    const int k0 = blockIdx.y * 32, n0 = blockIdx.x * 32;
    const int r = threadIdx.x >> 3, c = (threadIdx.x & 7) * 4;
    float4 v = *(const float4*)&src[(size_t)(k0 + r) * srcld + n0 + c];
    tile[r][c + 0] = v.x; tile[r][c + 1] = v.y;
    tile[r][c + 2] = v.z; tile[r][c + 3] = v.w;
    __syncthreads();
    const int nr = threadIdx.x >> 3, kc = (threadIdx.x & 7) * 4;
    ushortx4 o;
    o[0] = f2b(tile[kc + 0][nr]);
    o[1] = f2b(tile[kc + 1][nr]);
    o[2] = f2b(tile[kc + 2][nr]);
    o[3] = f2b(tile[kc + 3][nr]);
    int n = n0 + nr;
    int drow;
    if (perm) {
        int g = n >> 10, rr = n & 1023;
        drow = (rr >> 4) * 64 + g * 16 + (rr & 15);
    } else drow = n;
    drow += rowoff;
    *(ushortx4*)&dst[(size_t)drow * dstld + coloff + k0 + kc] = o;
}

// ---------------- 128x128 MFMA GEMM with global_load_lds ------------------
__global__ __launch_bounds__(256) void gemm_bf16_128(
    const unsigned short* __restrict__ A, int lda,
    const unsigned short* __restrict__ BT, int ldbt, int K,
    float* __restrict__ Cf, unsigned short* __restrict__ Cb,
    int ldc, int ncols, const float* __restrict__ bias)
{
    __shared__ __align__(16) unsigned short As[128 * 32];
    __shared__ __align__(16) unsigned short Bs[128 * 32];
    const int tid = threadIdx.x, wave = tid >> 6, lane = tid & 63;
    const int q = lane >> 4, lm = lane & 15;
    const int wr = wave >> 1, wc = wave & 1;
    const int m0 = blockIdx.y * 128, n0 = blockIdx.x * 128;
    const int srow = lane >> 2;
    const int gch = (lane & 3) ^ ((lane >> 3) & 3);
    const unsigned short* Ag0 = A + (size_t)(m0 + wave * 32 + srow) * lda + gch * 8;
    const unsigned short* Ag1 = Ag0 + (size_t)16 * lda;
    const unsigned short* Bg0 = BT + (size_t)(n0 + wave * 32 + srow) * ldbt + gch * 8;
    const unsigned short* Bg1 = Bg0 + (size_t)16 * ldbt;
    unsigned short* Al0 = &As[(wave * 32) * 32];
    unsigned short* Al1 = &As[(wave * 32 + 16) * 32];
    unsigned short* Bl0 = &Bs[(wave * 32) * 32];
    unsigned short* Bl1 = &Bs[(wave * 32 + 16) * 32];

    const floatx4 z4 = {0.f, 0.f, 0.f, 0.f};
    floatx4 acc[4][4];
#pragma unroll
    for (int i = 0; i < 4; i++)
#pragma unroll
        for (int j = 0; j < 4; j++) acc[i][j] = z4;
    const int ach = ((q ^ ((lm >> 1) & 3))) * 8;

    for (int kb = 0; kb < K; kb += 32) {
        ld_lds16(Ag0 + kb, Al0);
        ld_lds16(Ag1 + kb, Al1);
        ld_lds16(Bg0 + kb, Bl0);
        ld_lds16(Bg1 + kb, Bl1);
        __syncthreads();
        short8 a[4], b[4];
#pragma unroll
        for (int i = 0; i < 4; i++) a[i] = *(const short8*)&As[(wr * 64 + i * 16 + lm) * 32 + ach];
#pragma unroll
        for (int j = 0; j < 4; j++) b[j] = *(const short8*)&Bs[(wc * 64 + j * 16 + lm) * 32 + ach];
#pragma unroll
        for (int i = 0; i < 4; i++)
#pragma unroll
            for (int j = 0; j < 4; j++)
                acc[i][j] = __builtin_amdgcn_mfma_f32_16x16x32_bf16(a[i], b[j], acc[i][j], 0, 0, 0);
        __syncthreads();
    }
    const int rb = m0 + wr * 64 + q * 4;
#pragma unroll
    for (int i = 0; i < 4; i++) {
#pragma unroll
        for (int j = 0; j < 4; j++) {
            int col = n0 + wc * 64 + j * 16 + lm;
            if (col < ncols) {
                float bv = bias ? bias[col] : 0.f;
#pragma unroll
                for (int r = 0; r < 4; r++) {
                    float v = acc[i][j][r] + bv;
                    size_t idx = (size_t)(rb + i * 16 + r) * ldc + col;
                    if (Cf) Cf[idx] = v;
                    if (Cb) Cb[idx] = f2b(v);
                }
            }
        }
    }
}

// -------------------- init h/c state + barrier zero --------------------
__global__ __launch_bounds__(256) void init_hc(
    const float* __restrict__ hidden, const float* __restrict__ cell,
    float* __restrict__ cb, unsigned short* __restrict__ hbf,
    unsigned int* __restrict__ bar)
{
    int idx = blockIdx.x * 256 + threadIdx.x;  // < 65536
    float h = hidden[idx], c = cell[idx];
    cb[idx] = c; hbf[idx] = f2b(h);
    if (blockIdx.x == 0 && threadIdx.x < 8) bar[threadIdx.x] = 0;
}

// ---------------------- the persistent recurrence kernel -------------------
__global__ __launch_bounds__(512, 1) void persist_k(
    const unsigned short* __restrict__ enc_bf,
    const unsigned short* __restrict__ keys_bf,
    const unsigned short* __restrict__ WcT,   // [5120][1024] rows 1024+ permuted
    const unsigned short* __restrict__ KcTp,  // [4096][1280] rows permuted
    const float* __restrict__ x,
    const float* __restrict__ b1v,
    const float* __restrict__ Vv,
    const float* __restrict__ bVv,
    const float* __restrict__ bz,
    unsigned short* __restrict__ hbf,
    float* __restrict__ cb,
    float* __restrict__ qzh,                  // [2][64][5120] f32 partials
    unsigned short* __restrict__ Axc,         // [64][1280] bf16
    unsigned short* __restrict__ Hall,        // [4096][1024] bf16
    float* __restrict__ scbuf,                // [64][128]
    float* __restrict__ out,
    unsigned int* __restrict__ bar)
{
    __shared__ __align__(16) unsigned char smem[25600];
    const int blk = blockIdx.x, tid = threadIdx.x;
    const int w = tid >> 6, lane = tid & 63;
    const int q = lane >> 4, lm = lane & 15;
    const int srow = lane >> 2;
    const int gch = (lane & 3) ^ ((lane >> 3) & 3);
    const int ach = (q ^ ((lm >> 1) & 3)) * 8;
    const floatx4 z4 = {0.f, 0.f, 0.f, 0.f};

    for (int t = 0; t < 64; t++) {
        // ================= Phase A: qzh = hbf @ WcT^T (splitK2, 160 jobs) ====
        if (blk < 160) {
            unsigned short* As = (unsigned short*)smem;            // [64][32]
            unsigned short* Bs = (unsigned short*)(smem + 4096);   // [64][32]
            const int n0 = (blk % 80) * 64;
            const int part = blk / 80;
            const int k0 = part * 512;
            const int sr4 = (w & 3) * 16 + srow;
            const unsigned short* Sg = (w < 4)
                ? hbf + (size_t)sr4 * 1024 + (k0 + gch * 8)
                : WcT + (size_t)(n0 + sr4) * 1024 + (k0 + gch * 8);
            unsigned short* Sl = ((w < 4) ? As : Bs) + (size_t)((w & 3) * 16) * 32;
            const int wr = w >> 1, wc = w & 1;
            floatx4 a0 = z4, a1 = z4;
            for (int kb = 0; kb < 512; kb += 32) {
                ld_lds16(Sg + kb, Sl);
                __syncthreads();
                short8 af  = *(const short8*)&As[(wr * 16 + lm) * 32 + ach];
                short8 bf0 = *(const short8*)&Bs[(wc * 32 + lm) * 32 + ach];
                short8 bf1 = *(const short8*)&Bs[(wc * 32 + 16 + lm) * 32 + ach];
                a0 = __builtin_amdgcn_mfma_f32_16x16x32_bf16(af, bf0, a0, 0, 0, 0);
                a1 = __builtin_amdgcn_mfma_f32_16x16x32_bf16(af, bf1, a1, 0, 0, 0);
                __syncthreads();
            }
            float* Cp = qzh + (size_t)part * 327680;
            const int rb = wr * 16 + q * 4;
#pragma unroll
            for (int j = 0; j < 2; j++) {
                int col = n0 + wc * 32 + j * 16 + lm;
                floatx4 av = j ? a1 : a0;
#pragma unroll
                for (int r = 0; r < 4; r++)
                    Cp[(size_t)(rb + r) * 5120 + col] = av[r];
            }
        }
        gbar(bar);

        // ================= Phase B: scores (all 256 blocks, 4/wave) ==========
        {
            const int gw = blk * 8 + w;          // 0..2047
            const int b = gw >> 5;
            const int s0 = (gw & 31) * 4;
            float qv[16], vv[16];
            const float* q0 = qzh + (size_t)b * 5120 + lane * 16;
            const float* q1 = q0 + 327680;
#pragma unroll
            for (int i = 0; i < 16; i++) {
                qv[i] = q0[i] + q1[i] + b1v[lane * 16 + i];
                vv[i] = Vv[lane * 16 + i];
            }
            const float bV0 = bVv[0];
            for (int si = 0; si < 4; si++) {
                const int s = s0 + si;
                const uint4* kp = (const uint4*)(keys_bf + ((size_t)(b * 128 + s)) * 1024 + lane * 16);
                uint4 ka = kp[0], kb4 = kp[1];
                float kf[16];
                unpack16(ka, kb4, kf);
                float part = 0.f;
#pragma unroll
                for (int i = 0; i < 16; i++) part += vv[i] * ftanh(qv[i] + kf[i]);
#pragma unroll
                for (int off = 32; off; off >>= 1) part += __shfl_xor(part, off);
                if (lane == 0) scbuf[b * 128 + s] = part + bV0;
            }
        }
        gbar(bar);

        // ============ Phase C: softmax + ctx (128 blocks: b x 512-col half) ==
        if (blk < 128) {
            float* attnv = (float*)smem;            // [128]
            float* sred  = (float*)(smem + 512);    // [2]
            float* sprt  = (float*)(smem + 576);    // [2][256][2]
            const int b = blk >> 1, chunk = blk & 1;
            if (tid < 128) attnv[tid] = scbuf[b * 128 + tid];
            __syncthreads();
            if (tid < 64) {
                float m = fmaxf(attnv[tid], attnv[tid + 64]);
#pragma unroll
                for (int off = 32; off; off >>= 1) m = fmaxf(m, __shfl_xor(m, off));
                if (tid == 0) sred[0] = m;
            }
            __syncthreads();
            const float smax = sred[0];
            if (tid < 128) attnv[tid] = __expf(attnv[tid] - smax);
            __syncthreads();
            if (tid < 64) {
                float s2 = attnv[tid] + attnv[tid + 64];
#pragma unroll
                for (int off = 32; off; off >>= 1) s2 += __shfl_xor(s2, off);
                if (tid == 0) sred[1] = s2;
            }
            __syncthreads();
            const float rs = __builtin_amdgcn_rcpf(sred[1]);
            {
                const int p = tid & 255, sh = tid >> 8;
                const int e0 = chunk * 512 + p * 2;
                const unsigned int* ep =
                    (const unsigned int*)(enc_bf + (size_t)b * 131072 + e0) + (size_t)sh * 64 * 512;
                float ax = 0.f, ay = 0.f;
#pragma unroll 4
                for (int s2 = 0; s2 < 64; s2++) {
                    float a = attnv[sh * 64 + s2];
                    unsigned int u = ep[(size_t)s2 * 512];
                    ax += a * b2f((unsigned short)(u & 0xffff));
                    ay += a * b2f((unsigned short)(u >> 16));
                }
                sprt[(sh * 256 + p) * 2] = ax;
                sprt[(sh * 256 + p) * 2 + 1] = ay;
            }
            __syncthreads();
            if (tid < 256) {
                float ax = (sprt[tid * 2] + sprt[(256 + tid) * 2]) * rs;
                float ay = (sprt[tid * 2 + 1] + sprt[(256 + tid) * 2 + 1]) * rs;
                *(unsigned int*)&Axc[b * 1280 + chunk * 512 + tid * 2] =
                    (unsigned int)f2b(ax) | ((unsigned int)f2b(ay) << 16);
            } else if (chunk == 0 && tid < 384) {
                int p = tid - 256;
                float x0 = x[((size_t)b * 64 + t) * 256 + p * 2];
                float x1 = x[((size_t)b * 64 + t) * 256 + p * 2 + 1];
                *(unsigned int*)&Axc[b * 1280 + 1024 + p * 2] =
                    (unsigned int)f2b(x0) | ((unsigned int)f2b(x1) << 16);
            }
        }
        gbar(bar);

        // ===== Phase D: zcx = Axc @ KcTp^T (intra-block splitK4) + gates =====
        if (blk < 128) {
            unsigned short* Asd = (unsigned short*)smem;           // [4][32*32]
            unsigned short* Bsd = (unsigned short*)(smem + 8192);  // [4][64*32]
            const int mh = blk & 1, T = blk >> 1;
            const int n0 = T * 64;
            const int ks = w >> 1, wr = w & 1;
            const int k0 = ks * 320;
            const unsigned short* Ag =
                Axc + (size_t)(mh * 32 + wr * 16 + srow) * 1280 + k0 + gch * 8;
            const unsigned short* Bg0 =
                KcTp + (size_t)(n0 + wr * 32 + srow) * 1280 + k0 + gch * 8;
            const unsigned short* Bg1 = Bg0 + (size_t)16 * 1280;
            unsigned short* Al  = Asd + ks * 1024 + (wr * 16) * 32;
            unsigned short* Bl0 = Bsd + ks * 2048 + (wr * 32) * 32;
            unsigned short* Bl1 = Bl0 + 16 * 32;
            floatx4 acc[4] = {z4, z4, z4, z4};
            for (int kb = 0; kb < 320; kb += 32) {
                ld_lds16(Ag + kb, Al);
                ld_lds16(Bg0 + kb, Bl0);
                ld_lds16(Bg1 + kb, Bl1);
                __syncthreads();
                short8 a = *(const short8*)&Asd[ks * 1024 + (wr * 16 + lm) * 32 + ach];
#pragma unroll
                for (int j = 0; j < 4; j++) {
                    short8 bb = *(const short8*)&Bsd[ks * 2048 + (j * 16 + lm) * 32 + ach];
                    acc[j] = __builtin_amdgcn_mfma_f32_16x16x32_bf16(a, bb, acc[j], 0, 0, 0);
                }
                __syncthreads();
            }
            float* red = (float*)smem;   // reuse staging LDS: [2][3][64][16]
            if (ks > 0) {
                float4* dst = (float4*)&red[((size_t)(wr * 3 + ks - 1) * 64 + lane) * 16];
#pragma unroll
                for (int j = 0; j < 4; j++)
                    dst[j] = (float4){acc[j][0], acc[j][1], acc[j][2], acc[j][3]};
            }
            __syncthreads();
            if (ks == 0) {
#pragma unroll
                for (int kk = 0; kk < 3; kk++) {
                    const float4* src = (const float4*)&red[((size_t)(wr * 3 + kk) * 64 + lane) * 16];
#pragma unroll
                    for (int j = 0; j < 4; j++) {
                        float4 v = src[j];
                        acc[j][0] += v.x; acc[j][1] += v.y; acc[j][2] += v.z; acc[j][3] += v.w;
                    }
                }
                const int r = T * 16 + lm;
                const int b0r = mh * 32 + wr * 16 + q * 4;
                float bzv[4];
#pragma unroll
                for (int g = 0; g < 4; g++) bzv[g] = bz[g * 1024 + r];
#pragma unroll
                for (int i = 0; i < 4; i++) {
                    const int b = b0r + i;
                    const float* zh0 = qzh + (size_t)b * 5120 + 1024 + T * 64 + lm;
                    const float* zh1 = zh0 + 327680;
                    float zi = acc[0][i] + zh0[0]  + zh1[0]  + bzv[0];
                    float zf = acc[1][i] + zh0[16] + zh1[16] + bzv[1];
                    float zg = acc[2][i] + zh0[32] + zh1[32] + bzv[2];
                    float zo = acc[3][i] + zh0[48] + zh1[48] + bzv[3];
                    float ii = fsig(zi), ff = fsig(zf), gg = ftanh(zg), oo = fsig(zo);
                    const int cidx = b * 1024 + r;
                    float cn = ff * cb[cidx] + ii * gg;
                    float hn = oo * ftanh(cn);
                    cb[cidx] = cn;
                    unsigned short hb = f2b(hn);
                    hbf[cidx] = hb;
                    Hall[((size_t)b * 64 + t) * 1024 + r] = hb;
                    if (t == 63) {
                        out[32768000 + cidx] = hn;
                        out[32833536 + cidx] = cn;
                    }
                }
            }
        }
        gbar(bar);
    }
}

// ---------------------------------------------------------------------------
extern "C" void kernel_launch(void* const* d_in, const int* in_sizes, int n_in,
                              void* d_out, int out_size, void* d_ws, size_t ws_size,
                              hipStream_t stream)
{
    const float* x      = (const float*)d_in[0];   // [64,64,256]
    const float* hidden = (const float*)d_in[1];
    const float* cell   = (const float*)d_in[2];
    const float* enc    = (const float*)d_in[3];   // [64,128,1024]
    const float* W1     = (const float*)d_in[4];   // [1024,1024]
    const float* b1     = (const float*)d_in[5];
    const float* W2     = (const float*)d_in[6];   // [1024,1024]
    const float* b2     = (const float*)d_in[7];
    const float* V      = (const float*)d_in[8];   // [1024]
    const float* bV     = (const float*)d_in[9];
    const float* Wk     = (const float*)d_in[10];  // [1280,4096]
    const float* rk     = (const float*)d_in[11];  // [1024,4096]
    const float* bz     = (const float*)d_in[12];  // [4096]
    const float* Wd     = (const float*)d_in[13];  // [1024,8000]
    const float* bd     = (const float*)d_in[14];  // [8000]
    float* out = (float*)d_out;

    char* ws = (char*)d_ws;
    unsigned short* enc_bf  = (unsigned short*)(ws + 0);          // 16,777,216
    unsigned short* keys_bf = (unsigned short*)(ws + 16777216);   // 16,777,216
    unsigned short* WcT     = (unsigned short*)(ws + 33554432);   // 10,485,760 [5120][1024]
    unsigned short* KcTp    = (unsigned short*)(ws + 44040192);   // 10,485,760 [4096][1280]
    unsigned short* WdT     = (unsigned short*)(ws + 54525952);   // 16,515,072 [8064][1024]
    unsigned short* Hall    = (unsigned short*)(ws + 71041024);   //  8,388,608 [4096][1024]
    unsigned short* W2T     = Hall;                               // dead before Hall written
    unsigned short* hbf     = (unsigned short*)(ws + 79429632);   //    131,072
    unsigned short* Axc     = (unsigned short*)(ws + 79560704);   //    163,840 [64][1280]
    float* qzh   = (float*)(ws + 79724544);                       //  2,621,440 [2][64][5120]
    float* cb    = (float*)(ws + 82345984);                       //    262,144
    float* scbuf = (float*)(ws + 82608128);                       //     32,768
    unsigned int* bar = (unsigned int*)(ws + 82640896);           //         64

    // ---- one-time conversions / transposes ----
    conv_f32_bf16<<<8192, 256, 0, stream>>>(enc, enc_bf, 8388608 / 4);
    transpose_conv<<<dim3(32, 32),  256, 0, stream>>>(W2, 1024, W2T, 1024, 0, 0, 0);
    transpose_conv<<<dim3(32, 32),  256, 0, stream>>>(W1, 1024, WcT, 1024, 0, 0, 0);
    transpose_conv<<<dim3(128, 32), 256, 0, stream>>>(rk, 4096, WcT, 1024, 0, 1024, 1);
    transpose_conv<<<dim3(128, 32), 256, 0, stream>>>(Wk, 4096, KcTp, 1280, 0, 0, 1);
    transpose_conv<<<dim3(128, 8),  256, 0, stream>>>(Wk + 1024 * 4096, 4096, KcTp, 1280, 1024, 0, 1);
    transpose_conv<<<dim3(250, 32), 256, 0, stream>>>(Wd, 8000, WdT, 1024, 0, 0, 0);
    init_hc<<<256, 256, 0, stream>>>(hidden, cell, cb, hbf, bar);

    // keys = enc @ W2 + b2 -> bf16 [8192][1024]
    gemm_bf16_128<<<dim3(8, 64), 256, 0, stream>>>(enc_bf, 1024, W2T, 1024, 1024,
                                                   nullptr, keys_bf, 1024, 1024, b2);

    // ---- the whole recurrence in ONE kernel ----
    persist_k<<<PERSIST_NB, 512, 0, stream>>>(enc_bf, keys_bf, WcT, KcTp, x,
                                              b1, V, bV, bz, hbf, cb, qzh, Axc,
                                              Hall, scbuf, out, bar);

    // logits = Hall @ Wd + bd -> out [4096][8000]
    gemm_bf16_128<<<dim3(63, 32), 256, 0, stream>>>(Hall, 1024, WdT, 1024, 1024,
                                                    out, nullptr, 8000, 8000, bd);
}